// Round 1
// baseline (2408.435 us; speedup 1.0000x reference)
//
#include <hip/hip_runtime.h>

#define N_NODES 50000
#define N_EDGES 500000
#define HEADS 6
#define CH 64
#define F_HID 384   // HEADS*CH
#define IN_DIM 131

static inline int cdiv(int a, int b) { return (a + b - 1) / b; }

// ---------------- CSR build (counting sort by dst) ----------------
__global__ void count_kernel(const int* __restrict__ ei, int* __restrict__ deg) {
  int e = blockIdx.x * blockDim.x + threadIdx.x;
  if (e < N_EDGES) atomicAdd(&deg[ei[N_EDGES + e]], 1);
}

__global__ void scan_kernel(const int* __restrict__ deg, int* __restrict__ off) {
  // single block, 256 threads, 4 elems/thread/chunk inclusive scan
  __shared__ int sdata[256];
  int tid = threadIdx.x;
  int carry = 0;
  if (tid == 0) off[0] = 0;
  for (int base = 0; base < N_NODES; base += 1024) {
    int idx0 = base + tid * 4;
    int v[4]; int s = 0;
#pragma unroll
    for (int j = 0; j < 4; j++) {
      v[j] = (idx0 + j < N_NODES) ? deg[idx0 + j] : 0;
      s += v[j];
    }
    sdata[tid] = s;
    __syncthreads();
    for (int o = 1; o < 256; o <<= 1) {
      int x = (tid >= o) ? sdata[tid - o] : 0;
      __syncthreads();
      sdata[tid] += x;
      __syncthreads();
    }
    int excl = sdata[tid] - s + carry;   // exclusive prefix of this thread
    int total = sdata[255];
    int run = excl;
#pragma unroll
    for (int j = 0; j < 4; j++) {
      run += v[j];
      if (idx0 + j < N_NODES) off[idx0 + j + 1] = run;
    }
    carry += total;
    __syncthreads();  // protect sdata before next chunk overwrites
  }
}

__global__ void scatter_kernel(const int* __restrict__ ei, int* __restrict__ cursor,
                               int* __restrict__ csr_src) {
  int e = blockIdx.x * blockDim.x + threadIdx.x;
  if (e < N_EDGES) {
    int d = ei[N_EDGES + e];
    int p = atomicAdd(&cursor[d], 1);
    csr_src[p] = ei[e];  // src node of this edge
  }
}

// ---------------- GEMM: O[M,384] = A[M,K] @ W[K,384], fp32 ----------------
#define BM 64
#define BN 64
#define BK 32

__global__ __launch_bounds__(256) void gemm_f32(const float* __restrict__ A,
                                                const float* __restrict__ W,
                                                float* __restrict__ O,
                                                int M, int K) {
  __shared__ __align__(16) float As[BK][BM + 4];  // +4 pad: conflict-light, keeps 16B align
  __shared__ __align__(16) float Bs[BK][BN];
  const int nb = F_HID / BN;  // 6
  int bm = blockIdx.x / nb;
  int bn = blockIdx.x % nb;
  int tid = threadIdx.x;
  int tx = tid & 15, ty = tid >> 4;
  int row0 = bm * BM;

  float acc[4][4] = {};

  for (int k0 = 0; k0 < K; k0 += BK) {
    // stage A tile [BM][BK] -> As[k][m]; linear l: consecutive tid -> consecutive k (coalesced)
#pragma unroll
    for (int i = 0; i < 8; i++) {
      int l = tid + i * 256;         // 0..2047
      int a_r = l >> 5;              // /32
      int a_k = l & 31;
      int gr = row0 + a_r, gk = k0 + a_k;
      float v = (gr < M && gk < K) ? A[(long)gr * K + gk] : 0.0f;
      As[a_k][a_r] = v;
    }
    // stage B tile [BK][BN]; consecutive tid -> consecutive col (coalesced)
#pragma unroll
    for (int i = 0; i < 8; i++) {
      int l = tid + i * 256;
      int b_k = l >> 6;              // /64
      int b_c = l & 63;
      int gk = k0 + b_k;
      float v = (gk < K) ? W[(long)gk * F_HID + bn * BN + b_c] : 0.0f;
      Bs[b_k][b_c] = v;
    }
    __syncthreads();

#pragma unroll
    for (int k = 0; k < BK; k++) {
      float4 av = *reinterpret_cast<const float4*>(&As[k][ty * 4]);
      float4 bv = *reinterpret_cast<const float4*>(&Bs[k][tx * 4]);
      float a_[4] = {av.x, av.y, av.z, av.w};
      float b_[4] = {bv.x, bv.y, bv.z, bv.w};
#pragma unroll
      for (int i = 0; i < 4; i++)
#pragma unroll
        for (int j = 0; j < 4; j++)
          acc[i][j] += a_[i] * b_[j];
    }
    __syncthreads();
  }

#pragma unroll
  for (int i = 0; i < 4; i++) {
    int row = row0 + ty * 4 + i;
    if (row < M) {
      float4 v = make_float4(acc[i][0], acc[i][1], acc[i][2], acc[i][3]);
      *reinterpret_cast<float4*>(&O[(long)row * F_HID + bn * BN + tx * 4]) = v;
    }
  }
}

// ---------------- attention dots: al_s/al_d [N,H] ----------------
__global__ void dots_kernel(const float* __restrict__ feat,
                            const float* __restrict__ a_src,
                            const float* __restrict__ a_dst,
                            float* __restrict__ al_s, float* __restrict__ al_d) {
  int n = (blockIdx.x * blockDim.x + threadIdx.x) >> 6;  // wave per node
  int lane = threadIdx.x & 63;
  if (n >= N_NODES) return;
#pragma unroll
  for (int h = 0; h < HEADS; h++) {
    float v = feat[(long)n * F_HID + h * CH + lane];
    float p = v * a_src[h * CH + lane];
    float q = v * a_dst[h * CH + lane];
#pragma unroll
    for (int o = 32; o; o >>= 1) {
      p += __shfl_xor(p, o);
      q += __shfl_xor(q, o);
    }
    if (lane == 0) {
      al_s[n * HEADS + h] = p;
      al_d[n * HEADS + h] = q;
    }
  }
}

// ---------------- softmax stats per (node, head) ----------------
__global__ void stats_kernel(const int* __restrict__ off, const int* __restrict__ csr_src,
                             const float* __restrict__ al_s, const float* __restrict__ al_d,
                             float* __restrict__ mbuf, float* __restrict__ rbuf) {
  int t = blockIdx.x * blockDim.x + threadIdx.x;
  if (t >= N_NODES * HEADS) return;
  int n = t / HEADS, h = t % HEADS;
  int s0 = off[n], s1 = off[n + 1];
  float ad = al_d[t];
  float m = -INFINITY;
  for (int i = s0; i < s1; i++) {
    float e = al_s[csr_src[i] * HEADS + h] + ad;
    e = e > 0.0f ? e : 0.2f * e;
    m = fmaxf(m, e);
  }
  float mm = (s1 > s0) ? m : 0.0f;  // isfinite fix for isolated nodes
  float sum = 0.0f;
  for (int i = s0; i < s1; i++) {
    float e = al_s[csr_src[i] * HEADS + h] + ad;
    e = e > 0.0f ? e : 0.2f * e;
    sum += __expf(e - mm);
  }
  mbuf[t] = mm;
  rbuf[t] = 1.0f / (sum + 1e-16f);
}

// ---------------- aggregation: out[n,h,c] = sum_e alpha * feat[src,h,c] ----------------
// MODE 0: += bias then ELU (hidden layers). MODE 1: raw (output layer, mean later).
template <int MODE>
__global__ __launch_bounds__(384) void agg_kernel(const float* __restrict__ feat,
                                                  const int* __restrict__ off,
                                                  const int* __restrict__ csr_src,
                                                  const float* __restrict__ al_s,
                                                  const float* __restrict__ al_d,
                                                  const float* __restrict__ mbuf,
                                                  const float* __restrict__ rbuf,
                                                  const float* __restrict__ bias,
                                                  float* __restrict__ out) {
  int n = blockIdx.x;
  int tid = threadIdx.x;        // h*64 + lane
  int h = tid >> 6;
  int s0 = off[n], s1 = off[n + 1];
  float ad = al_d[n * HEADS + h];
  float mm = mbuf[n * HEADS + h];
  float rr = rbuf[n * HEADS + h];
  float acc = 0.0f;
  for (int i = s0; i < s1; i++) {
    int s = csr_src[i];
    float e = al_s[s * HEADS + h] + ad;
    e = e > 0.0f ? e : 0.2f * e;
    float w = __expf(e - mm) * rr;
    acc += w * feat[(long)s * F_HID + tid];
  }
  if (MODE == 0) {
    float v = acc + bias[tid];
    v = v > 0.0f ? v : (__expf(v) - 1.0f);  // ELU, alpha=1
    out[(long)n * F_HID + tid] = v;
  } else {
    out[(long)n * F_HID + tid] = acc;
  }
}

// ---------------- output head mean + bias ----------------
__global__ void mean_kernel(const float* __restrict__ agg, const float* __restrict__ b3,
                            float* __restrict__ out) {
  int t = blockIdx.x * blockDim.x + threadIdx.x;
  if (t >= N_NODES * CH) return;
  int n = t >> 6, c = t & 63;
  float s = 0.0f;
#pragma unroll
  for (int h = 0; h < HEADS; h++) s += agg[(long)n * F_HID + h * CH + c];
  out[t] = s * (1.0f / 6.0f) + b3[c];
}

extern "C" void kernel_launch(void* const* d_in, const int* in_sizes, int n_in,
                              void* d_out, int out_size, void* d_ws, size_t ws_size,
                              hipStream_t stream) {
  const float* x  = (const float*)d_in[0];
  const int*   ei = (const int*)d_in[1];
  const float* W_[4]  = {(const float*)d_in[2], (const float*)d_in[6],
                         (const float*)d_in[10], (const float*)d_in[14]};
  const float* AS_[4] = {(const float*)d_in[3], (const float*)d_in[7],
                         (const float*)d_in[11], (const float*)d_in[15]};
  const float* AD_[4] = {(const float*)d_in[4], (const float*)d_in[8],
                         (const float*)d_in[12], (const float*)d_in[16]};
  const float* B_[4]  = {(const float*)d_in[5], (const float*)d_in[9],
                         (const float*)d_in[13], (const float*)d_in[17]};
  float* out = (float*)d_out;

  float* wsf = (float*)d_ws;
  float* bufA = wsf;                       // [N, 384] feat (GEMM out)
  float* bufB = bufA + (long)N_NODES * F_HID;  // [N, 384] layer output / GEMM in
  float* als  = bufB + (long)N_NODES * F_HID;  // [N, 6]
  float* ald  = als + N_NODES * HEADS;
  float* mb   = ald + N_NODES * HEADS;
  float* rb   = mb + N_NODES * HEADS;
  int* off    = (int*)(rb + N_NODES * HEADS);  // [N+1]
  int* cur    = off + (N_NODES + 1);           // [N]
  int* deg    = cur + N_NODES;                 // [N]
  int* csr    = deg + N_NODES;                 // [E]

  // ---- CSR build (every call; deterministic up to fp-atomic ordering) ----
  hipMemsetAsync(deg, 0, N_NODES * sizeof(int), stream);
  count_kernel<<<cdiv(N_EDGES, 256), 256, 0, stream>>>(ei, deg);
  scan_kernel<<<1, 256, 0, stream>>>(deg, off);
  hipMemcpyAsync(cur, off, N_NODES * sizeof(int), hipMemcpyDeviceToDevice, stream);
  scatter_kernel<<<cdiv(N_EDGES, 256), 256, 0, stream>>>(ei, cur, csr);

  const int gemm_grid_m = cdiv(N_NODES, BM) * (F_HID / BN);
  const int dots_grid = cdiv(N_NODES, 4);
  const int stats_grid = cdiv(N_NODES * HEADS, 256);
  const int mean_grid = cdiv(N_NODES * CH, 256);

  // ---- Layer 0: x[131] -> bufA feat -> bufB (ELU) ----
  gemm_f32<<<gemm_grid_m, 256, 0, stream>>>(x, W_[0], bufA, N_NODES, IN_DIM);
  dots_kernel<<<dots_grid, 256, 0, stream>>>(bufA, AS_[0], AD_[0], als, ald);
  stats_kernel<<<stats_grid, 256, 0, stream>>>(off, csr, als, ald, mb, rb);
  agg_kernel<0><<<N_NODES, 384, 0, stream>>>(bufA, off, csr, als, ald, mb, rb, B_[0], bufB);

  // ---- Layers 1, 2: bufB -> bufA feat -> bufB ----
  for (int l = 1; l <= 2; l++) {
    gemm_f32<<<gemm_grid_m, 256, 0, stream>>>(bufB, W_[l], bufA, N_NODES, F_HID);
    dots_kernel<<<dots_grid, 256, 0, stream>>>(bufA, AS_[l], AD_[l], als, ald);
    stats_kernel<<<stats_grid, 256, 0, stream>>>(off, csr, als, ald, mb, rb);
    agg_kernel<0><<<N_NODES, 384, 0, stream>>>(bufA, off, csr, als, ald, mb, rb, B_[l], bufB);
  }

  // ---- Layer 3: bufB -> bufA feat -> bufB (raw agg) -> mean+bias -> out ----
  gemm_f32<<<gemm_grid_m, 256, 0, stream>>>(bufB, W_[3], bufA, N_NODES, F_HID);
  dots_kernel<<<dots_grid, 256, 0, stream>>>(bufA, AS_[3], AD_[3], als, ald);
  stats_kernel<<<stats_grid, 256, 0, stream>>>(off, csr, als, ald, mb, rb);
  agg_kernel<1><<<N_NODES, 384, 0, stream>>>(bufA, off, csr, als, ald, mb, rb, nullptr, bufB);
  mean_kernel<<<mean_grid, 256, 0, stream>>>(bufB, B_[3], out);
}

// Round 2
// 1514.940 us; speedup vs baseline: 1.5898x; 1.5898x over previous
//
#include <hip/hip_runtime.h>

#define N_NODES 50000
#define M_PAD 50048      // N_NODES rounded up to 128
#define N_EDGES 500000
#define HEADS 6
#define CH 64
#define F_HID 384
#define IN_DIM 131
#define K0PAD 160        // layer-0 K padded to multiple of 32

static inline int cdiv(int a, int b) { return (a + b - 1) / b; }

typedef __attribute__((ext_vector_type(8))) __bf16 bf16x8;
typedef __attribute__((ext_vector_type(4))) float f32x4;
typedef __attribute__((ext_vector_type(8))) unsigned short us8;

// round-to-nearest-even fp32 -> bf16 split: v ~= hi + lo
__device__ __forceinline__ void bsplit(float v, unsigned short& h, unsigned short& l) {
  unsigned u = __builtin_bit_cast(unsigned, v);
  unsigned hr = (u + 0x7FFFu + ((u >> 16) & 1u)) >> 16;
  h = (unsigned short)hr;
  float hf = __builtin_bit_cast(float, hr << 16);
  float r = v - hf;
  unsigned u2 = __builtin_bit_cast(unsigned, r);
  unsigned lr = (u2 + 0x7FFFu + ((u2 >> 16) & 1u)) >> 16;
  l = (unsigned short)lr;
}

__device__ __forceinline__ void gload16(const void* g, void* lds) {
  __builtin_amdgcn_global_load_lds((const __attribute__((address_space(1))) void*)g,
                                   (__attribute__((address_space(3))) void*)lds, 16, 0, 0);
}

// ---------------- CSR build ----------------
__global__ void count_kernel(const int* __restrict__ ei, int* __restrict__ deg) {
  int e = blockIdx.x * blockDim.x + threadIdx.x;
  if (e < N_EDGES) atomicAdd(&deg[ei[N_EDGES + e]], 1);
}

__global__ void scan_kernel(const int* __restrict__ deg, int* __restrict__ off) {
  __shared__ int sdata[256];
  int tid = threadIdx.x;
  int carry = 0;
  if (tid == 0) off[0] = 0;
  for (int base = 0; base < N_NODES; base += 1024) {
    int idx0 = base + tid * 4;
    int v[4]; int s = 0;
#pragma unroll
    for (int j = 0; j < 4; j++) {
      v[j] = (idx0 + j < N_NODES) ? deg[idx0 + j] : 0;
      s += v[j];
    }
    sdata[tid] = s;
    __syncthreads();
    for (int o = 1; o < 256; o <<= 1) {
      int x = (tid >= o) ? sdata[tid - o] : 0;
      __syncthreads();
      sdata[tid] += x;
      __syncthreads();
    }
    int excl = sdata[tid] - s + carry;
    int total = sdata[255];
    int run = excl;
#pragma unroll
    for (int j = 0; j < 4; j++) {
      run += v[j];
      if (idx0 + j < N_NODES) off[idx0 + j + 1] = run;
    }
    carry += total;
    __syncthreads();
  }
}

__global__ void scatter_kernel(const int* __restrict__ ei, int* __restrict__ cursor,
                               int* __restrict__ csr_src) {
  int e = blockIdx.x * blockDim.x + threadIdx.x;
  if (e < N_EDGES) {
    int d = ei[N_EDGES + e];
    int p = atomicAdd(&cursor[d], 1);
    csr_src[p] = ei[e];
  }
}

// ---------------- packers: fp32 -> interleaved, pre-swizzled split-bf16 ----------------
// Packed layout per row r (Kpad k's): per 32-k step kt, a 128B group of 8x16B chunks.
// Logical chunk c = 2*kb + s (kb = k-block of 8, s = 0:hi 1:lo) stored at p = c ^ (r&7).

// x [N_NODES][131] -> xp [M_PAD][2*K0PAD] bf16
__global__ void convert_x(const float* __restrict__ x, unsigned short* __restrict__ xp) {
  int t = blockIdx.x * blockDim.x + threadIdx.x;
  const int npc = K0PAD / 8;  // 20 chunks of 8 per row
  if (t >= M_PAD * npc) return;
  int r = t / npc, g = t % npc;
  int kt = g >> 2, kb = g & 3;
  int k0 = kt * 32 + kb * 8;
  us8 hv, lv;
#pragma unroll
  for (int j = 0; j < 8; j++) {
    int k = k0 + j;
    float v = (r < N_NODES && k < IN_DIM) ? x[(long)r * IN_DIM + k] : 0.0f;
    unsigned short h, l; bsplit(v, h, l);
    hv[j] = h; lv[j] = l;
  }
  char* base = (char*)xp + (size_t)r * (4 * K0PAD) + kt * 128;
  int x7 = r & 7;
  *(us8*)(base + (((2 * kb) ^ x7) << 4)) = hv;
  *(us8*)(base + (((2 * kb + 1) ^ x7) << 4)) = lv;
}

// W [Kreal][384] -> Wt [384][2*Kpad] bf16 (transposed: row = out-col n)
__global__ void convert_W(const float* __restrict__ W, unsigned short* __restrict__ Wt,
                          int Kreal, int Kpad) {
  int t = blockIdx.x * blockDim.x + threadIdx.x;
  int npc = Kpad >> 3;
  if (t >= F_HID * npc) return;
  int n = t / npc, g = t % npc;
  int kt = g >> 2, kb = g & 3;
  int k0 = kt * 32 + kb * 8;
  us8 hv, lv;
#pragma unroll
  for (int j = 0; j < 8; j++) {
    int k = k0 + j;
    float v = (k < Kreal) ? W[(long)k * F_HID + n] : 0.0f;
    unsigned short h, l; bsplit(v, h, l);
    hv[j] = h; lv[j] = l;
  }
  char* base = (char*)Wt + (size_t)n * (4 * Kpad) + kt * 128;
  int x7 = n & 7;
  *(us8*)(base + (((2 * kb) ^ x7) << 4)) = hv;
  *(us8*)(base + (((2 * kb + 1) ^ x7) << 4)) = lv;
}

// ---------------- split-bf16 MFMA GEMM: O[M,384] = A[M,K] @ W[K,384] ----------------
// Ap: [M_PAD][2K] packed rows, Bp: [384][2K] packed rows (W^T), O fp32 [M][384].
template <int K>
__global__ __launch_bounds__(256) void gemm_mfma(const unsigned short* __restrict__ Ap,
                                                 const unsigned short* __restrict__ Bp,
                                                 float* __restrict__ O) {
  constexpr int NKT = K / 32;
  constexpr size_t RB = 4 * K;  // bytes per packed row
  __shared__ __align__(16) char smA[16384];
  __shared__ __align__(16) char smB[16384];
  int bm = blockIdx.x / 3, bn = blockIdx.x % 3;
  int row0 = bm * 128, col0 = bn * 128;
  int tid = threadIdx.x, lane = tid & 63, wv = tid >> 6;
  int wy = wv >> 1, wx = wv & 1;

  f32x4 acc[4][4];
#pragma unroll
  for (int i = 0; i < 4; i++)
#pragma unroll
    for (int j = 0; j < 4; j++) acc[i][j] = (f32x4)0.0f;

  const char* Ab = (const char*)Ap + (size_t)row0 * RB;
  const char* Bb = (const char*)Bp + (size_t)col0 * RB;

  int kb2 = (lane >> 4) * 2;  // 2*kblock
  int x7 = lane & 7;
  int rA = wy * 64 + (lane & 15);
  int rB = wx * 64 + (lane & 15);

  for (int kt = 0; kt < NKT; ++kt) {
    // stage 16KB A + 16KB B: 4 waves x 4 insts x 64 lanes x 16B each
#pragma unroll
    for (int i = 0; i < 4; ++i) {
      int b = wv * 4096 + i * 1024;
      int bl = b + lane * 16;
      int r = bl >> 7, q = bl & 127;
      gload16(Ab + (size_t)r * RB + kt * 128 + q, smA + b);
      gload16(Bb + (size_t)r * RB + kt * 128 + q, smB + b);
    }
    __syncthreads();

    bf16x8 ah[4], alo[4], bh[4], blo[4];
#pragma unroll
    for (int mf = 0; mf < 4; ++mf) {
      const char* p = smA + (rA + mf * 16) * 128;
      ah[mf]  = *(const bf16x8*)(p + ((kb2 ^ x7) << 4));
      alo[mf] = *(const bf16x8*)(p + (((kb2 + 1) ^ x7) << 4));
    }
#pragma unroll
    for (int nf = 0; nf < 4; ++nf) {
      const char* p = smB + (rB + nf * 16) * 128;
      bh[nf]  = *(const bf16x8*)(p + ((kb2 ^ x7) << 4));
      blo[nf] = *(const bf16x8*)(p + (((kb2 + 1) ^ x7) << 4));
    }
#pragma unroll
    for (int mf = 0; mf < 4; ++mf)
#pragma unroll
      for (int nf = 0; nf < 4; ++nf) {
        acc[mf][nf] = __builtin_amdgcn_mfma_f32_16x16x32_bf16(ah[mf], bh[nf], acc[mf][nf], 0, 0, 0);
        acc[mf][nf] = __builtin_amdgcn_mfma_f32_16x16x32_bf16(alo[mf], bh[nf], acc[mf][nf], 0, 0, 0);
        acc[mf][nf] = __builtin_amdgcn_mfma_f32_16x16x32_bf16(ah[mf], blo[nf], acc[mf][nf], 0, 0, 0);
      }
    __syncthreads();
  }

  int cr = (lane >> 4) * 4, cc = lane & 15;
#pragma unroll
  for (int mf = 0; mf < 4; ++mf)
#pragma unroll
    for (int r = 0; r < 4; ++r) {
      int row = row0 + wy * 64 + mf * 16 + cr + r;
      if (row < N_NODES) {
#pragma unroll
        for (int nf = 0; nf < 4; ++nf)
          O[(size_t)row * F_HID + col0 + wx * 64 + nf * 16 + cc] = acc[mf][nf][r];
      }
    }
}

// ---------------- attention dots ----------------
__global__ void dots_kernel(const float* __restrict__ feat,
                            const float* __restrict__ a_src,
                            const float* __restrict__ a_dst,
                            float* __restrict__ al_s, float* __restrict__ al_d) {
  int n = (blockIdx.x * blockDim.x + threadIdx.x) >> 6;
  int lane = threadIdx.x & 63;
  if (n >= N_NODES) return;
#pragma unroll
  for (int h = 0; h < HEADS; h++) {
    float v = feat[(long)n * F_HID + h * CH + lane];
    float p = v * a_src[h * CH + lane];
    float q = v * a_dst[h * CH + lane];
#pragma unroll
    for (int o = 32; o; o >>= 1) {
      p += __shfl_xor(p, o);
      q += __shfl_xor(q, o);
    }
    if (lane == 0) {
      al_s[n * HEADS + h] = p;
      al_d[n * HEADS + h] = q;
    }
  }
}

// ---------------- softmax stats ----------------
__global__ void stats_kernel(const int* __restrict__ off, const int* __restrict__ csr_src,
                             const float* __restrict__ al_s, const float* __restrict__ al_d,
                             float* __restrict__ mbuf, float* __restrict__ rbuf) {
  int t = blockIdx.x * blockDim.x + threadIdx.x;
  if (t >= N_NODES * HEADS) return;
  int n = t / HEADS, h = t % HEADS;
  int s0 = off[n], s1 = off[n + 1];
  float ad = al_d[t];
  float m = -INFINITY;
  for (int i = s0; i < s1; i++) {
    float e = al_s[csr_src[i] * HEADS + h] + ad;
    e = e > 0.0f ? e : 0.2f * e;
    m = fmaxf(m, e);
  }
  float mm = (s1 > s0) ? m : 0.0f;
  float sum = 0.0f;
  for (int i = s0; i < s1; i++) {
    float e = al_s[csr_src[i] * HEADS + h] + ad;
    e = e > 0.0f ? e : 0.2f * e;
    sum += __expf(e - mm);
  }
  mbuf[t] = mm;
  rbuf[t] = 1.0f / (sum + 1e-16f);
}

// ---------------- aggregation (hidden): bias+ELU, emit packed split-bf16 ----------------
__global__ __launch_bounds__(384) void agg_hidden(const float* __restrict__ feat,
                                                  const int* __restrict__ off,
                                                  const int* __restrict__ csr_src,
                                                  const float* __restrict__ al_s,
                                                  const float* __restrict__ al_d,
                                                  const float* __restrict__ mbuf,
                                                  const float* __restrict__ rbuf,
                                                  const float* __restrict__ bias,
                                                  unsigned short* __restrict__ Apk) {
  int n = blockIdx.x;
  int tid = threadIdx.x;  // = k in [0,384)
  int h = tid >> 6;
  int s0 = off[n], s1 = off[n + 1];
  float ad = al_d[n * HEADS + h];
  float mm = mbuf[n * HEADS + h];
  float rr = rbuf[n * HEADS + h];
  float acc = 0.0f;
  for (int i = s0; i < s1; i++) {
    int s = csr_src[i];
    float e = al_s[s * HEADS + h] + ad;
    e = e > 0.0f ? e : 0.2f * e;
    float w = __expf(e - mm) * rr;
    acc += w * feat[(long)s * F_HID + tid];
  }
  float v = acc + bias[tid];
  v = v > 0.0f ? v : (__expf(v) - 1.0f);  // ELU
  unsigned short hh, ll; bsplit(v, hh, ll);
  int kt = tid >> 5, kb = (tid >> 3) & 3, j = tid & 7;
  char* base = (char*)Apk + (size_t)n * (4 * F_HID) + kt * 128;
  int x7 = n & 7;
  *(unsigned short*)(base + (((2 * kb) ^ x7) << 4) + j * 2) = hh;
  *(unsigned short*)(base + (((2 * kb + 1) ^ x7) << 4) + j * 2) = ll;
}

// ---------------- aggregation (output): raw agg + mean over heads + bias ----------------
__global__ __launch_bounds__(384) void agg_out(const float* __restrict__ feat,
                                               const int* __restrict__ off,
                                               const int* __restrict__ csr_src,
                                               const float* __restrict__ al_s,
                                               const float* __restrict__ al_d,
                                               const float* __restrict__ mbuf,
                                               const float* __restrict__ rbuf,
                                               const float* __restrict__ b3,
                                               float* __restrict__ out) {
  __shared__ float red[384];
  int n = blockIdx.x;
  int tid = threadIdx.x;
  int h = tid >> 6;
  int s0 = off[n], s1 = off[n + 1];
  float ad = al_d[n * HEADS + h];
  float mm = mbuf[n * HEADS + h];
  float rr = rbuf[n * HEADS + h];
  float acc = 0.0f;
  for (int i = s0; i < s1; i++) {
    int s = csr_src[i];
    float e = al_s[s * HEADS + h] + ad;
    e = e > 0.0f ? e : 0.2f * e;
    float w = __expf(e - mm) * rr;
    acc += w * feat[(long)s * F_HID + tid];
  }
  red[tid] = acc;
  __syncthreads();
  if (tid < CH) {
    float s = 0.0f;
#pragma unroll
    for (int hh = 0; hh < HEADS; hh++) s += red[hh * CH + tid];
    out[(long)n * CH + tid] = s * (1.0f / 6.0f) + b3[tid];
  }
}

extern "C" void kernel_launch(void* const* d_in, const int* in_sizes, int n_in,
                              void* d_out, int out_size, void* d_ws, size_t ws_size,
                              hipStream_t stream) {
  const float* x  = (const float*)d_in[0];
  const int*   ei = (const int*)d_in[1];
  const float* W_[4]  = {(const float*)d_in[2], (const float*)d_in[6],
                         (const float*)d_in[10], (const float*)d_in[14]};
  const float* AS_[4] = {(const float*)d_in[3], (const float*)d_in[7],
                         (const float*)d_in[11], (const float*)d_in[15]};
  const float* AD_[4] = {(const float*)d_in[4], (const float*)d_in[8],
                         (const float*)d_in[12], (const float*)d_in[16]};
  const float* B_[4]  = {(const float*)d_in[5], (const float*)d_in[9],
                         (const float*)d_in[13], (const float*)d_in[17]};
  float* out = (float*)d_out;

  // ---- workspace layout (bytes) ----
  char* w = (char*)d_ws;
  float* bufA = (float*)w;                               // [N,384] f32 GEMM out
  w += (size_t)N_NODES * F_HID * 4;                      // 76,800,000
  unsigned short* Apk = (unsigned short*)w;              // [M_PAD][2*384] bf16 packed (also xp [M_PAD][2*160])
  w += (size_t)M_PAD * 2 * F_HID * 2;                    // 76,873,728
  unsigned short* Wt0 = (unsigned short*)w; w += (size_t)F_HID * 2 * K0PAD * 2;
  unsigned short* Wt1 = (unsigned short*)w; w += (size_t)F_HID * 2 * F_HID * 2;
  unsigned short* Wt2 = (unsigned short*)w; w += (size_t)F_HID * 2 * F_HID * 2;
  unsigned short* Wt3 = (unsigned short*)w; w += (size_t)F_HID * 2 * F_HID * 2;
  float* als = (float*)w; w += (size_t)N_NODES * HEADS * 4;
  float* ald = (float*)w; w += (size_t)N_NODES * HEADS * 4;
  float* mb  = (float*)w; w += (size_t)N_NODES * HEADS * 4;
  float* rb  = (float*)w; w += (size_t)N_NODES * HEADS * 4;
  int* off = (int*)w; w += (N_NODES + 1) * 4;
  int* cur = (int*)w; w += N_NODES * 4;
  int* deg = (int*)w; w += N_NODES * 4;
  int* csr = (int*)w;

  // ---- CSR build ----
  hipMemsetAsync(deg, 0, N_NODES * sizeof(int), stream);
  count_kernel<<<cdiv(N_EDGES, 256), 256, 0, stream>>>(ei, deg);
  scan_kernel<<<1, 256, 0, stream>>>(deg, off);
  hipMemcpyAsync(cur, off, N_NODES * sizeof(int), hipMemcpyDeviceToDevice, stream);
  scatter_kernel<<<cdiv(N_EDGES, 256), 256, 0, stream>>>(ei, cur, csr);

  // ---- pack inputs ----
  convert_x<<<cdiv(M_PAD * (K0PAD / 8), 256), 256, 0, stream>>>(x, Apk);
  convert_W<<<cdiv(F_HID * (K0PAD / 8), 256), 256, 0, stream>>>(W_[0], Wt0, IN_DIM, K0PAD);
  convert_W<<<cdiv(F_HID * (F_HID / 8), 256), 256, 0, stream>>>(W_[1], Wt1, F_HID, F_HID);
  convert_W<<<cdiv(F_HID * (F_HID / 8), 256), 256, 0, stream>>>(W_[2], Wt2, F_HID, F_HID);
  convert_W<<<cdiv(F_HID * (F_HID / 8), 256), 256, 0, stream>>>(W_[3], Wt3, F_HID, F_HID);
  // zero the padded tail rows of the K=384 packed plane (rows N_NODES..M_PAD)
  hipMemsetAsync((char*)Apk + (size_t)N_NODES * 4 * F_HID, 0,
                 (size_t)(M_PAD - N_NODES) * 4 * F_HID, stream);

  const int gemm_grid = cdiv(N_NODES, 128) * 3;  // 391*3
  const int dots_grid = cdiv(N_NODES, 4);
  const int stats_grid = cdiv(N_NODES * HEADS, 256);

  // ---- Layer 0 (K=160 packed) ----
  gemm_mfma<K0PAD><<<gemm_grid, 256, 0, stream>>>(Apk, Wt0, bufA);
  dots_kernel<<<dots_grid, 256, 0, stream>>>(bufA, AS_[0], AD_[0], als, ald);
  stats_kernel<<<stats_grid, 256, 0, stream>>>(off, csr, als, ald, mb, rb);
  agg_hidden<<<N_NODES, 384, 0, stream>>>(bufA, off, csr, als, ald, mb, rb, B_[0], Apk);

  // ---- Layers 1,2 (K=384) ----
  gemm_mfma<F_HID><<<gemm_grid, 256, 0, stream>>>(Apk, Wt1, bufA);
  dots_kernel<<<dots_grid, 256, 0, stream>>>(bufA, AS_[1], AD_[1], als, ald);
  stats_kernel<<<stats_grid, 256, 0, stream>>>(off, csr, als, ald, mb, rb);
  agg_hidden<<<N_NODES, 384, 0, stream>>>(bufA, off, csr, als, ald, mb, rb, B_[1], Apk);

  gemm_mfma<F_HID><<<gemm_grid, 256, 0, stream>>>(Apk, Wt2, bufA);
  dots_kernel<<<dots_grid, 256, 0, stream>>>(bufA, AS_[2], AD_[2], als, ald);
  stats_kernel<<<stats_grid, 256, 0, stream>>>(off, csr, als, ald, mb, rb);
  agg_hidden<<<N_NODES, 384, 0, stream>>>(bufA, off, csr, als, ald, mb, rb, B_[2], Apk);

  // ---- Layer 3 (K=384, mean over heads) ----
  gemm_mfma<F_HID><<<gemm_grid, 256, 0, stream>>>(Apk, Wt3, bufA);
  dots_kernel<<<dots_grid, 256, 0, stream>>>(bufA, AS_[3], AD_[3], als, ald);
  stats_kernel<<<stats_grid, 256, 0, stream>>>(off, csr, als, ald, mb, rb);
  agg_out<<<N_NODES, 384, 0, stream>>>(bufA, off, csr, als, ald, mb, rb, B_[3], out);
}

// Round 4
// 997.326 us; speedup vs baseline: 2.4149x; 1.5190x over previous
//
#include <hip/hip_runtime.h>

#define N_NODES 50000
#define M_PAD 50048      // N_NODES rounded up to 128
#define N_EDGES 500000
#define HEADS 6
#define CH 64
#define F_HID 384
#define IN_DIM 131
#define K0PAD 160        // layer-0 K padded to multiple of 32

static inline int cdiv(int a, int b) { return (a + b - 1) / b; }

typedef __attribute__((ext_vector_type(8))) __bf16 bf16x8;
typedef __attribute__((ext_vector_type(4))) float f32x4;
typedef __attribute__((ext_vector_type(8))) unsigned short us8;
typedef __attribute__((ext_vector_type(4))) unsigned short us4;
typedef __attribute__((ext_vector_type(4))) _Float16 f16x4;

// round-to-nearest-even fp32 -> bf16 split: v ~= hi + lo
__device__ __forceinline__ void bsplit(float v, unsigned short& h, unsigned short& l) {
  unsigned u = __builtin_bit_cast(unsigned, v);
  unsigned hr = (u + 0x7FFFu + ((u >> 16) & 1u)) >> 16;
  h = (unsigned short)hr;
  float hf = __builtin_bit_cast(float, hr << 16);
  float r = v - hf;
  unsigned u2 = __builtin_bit_cast(unsigned, r);
  unsigned lr = (u2 + 0x7FFFu + ((u2 >> 16) & 1u)) >> 16;
  l = (unsigned short)lr;
}

__device__ __forceinline__ void gload16(const void* g, void* lds) {
  __builtin_amdgcn_global_load_lds((const __attribute__((address_space(1))) void*)g,
                                   (__attribute__((address_space(3))) void*)lds, 16, 0, 0);
}

// ---------------- CSR build ----------------
__global__ void count_kernel(const int* __restrict__ ei, int* __restrict__ deg) {
  int e = blockIdx.x * blockDim.x + threadIdx.x;
  if (e < N_EDGES) atomicAdd(&deg[ei[N_EDGES + e]], 1);
}

__global__ void scan_kernel(const int* __restrict__ deg, int* __restrict__ off) {
  __shared__ int sdata[256];
  int tid = threadIdx.x;
  int carry = 0;
  if (tid == 0) off[0] = 0;
  for (int base = 0; base < N_NODES; base += 1024) {
    int idx0 = base + tid * 4;
    int v[4]; int s = 0;
#pragma unroll
    for (int j = 0; j < 4; j++) {
      v[j] = (idx0 + j < N_NODES) ? deg[idx0 + j] : 0;
      s += v[j];
    }
    sdata[tid] = s;
    __syncthreads();
    for (int o = 1; o < 256; o <<= 1) {
      int x = (tid >= o) ? sdata[tid - o] : 0;
      __syncthreads();
      sdata[tid] += x;
      __syncthreads();
    }
    int excl = sdata[tid] - s + carry;
    int total = sdata[255];
    int run = excl;
#pragma unroll
    for (int j = 0; j < 4; j++) {
      run += v[j];
      if (idx0 + j < N_NODES) off[idx0 + j + 1] = run;
    }
    carry += total;
    __syncthreads();
  }
}

__global__ void scatter_kernel(const int* __restrict__ ei, int* __restrict__ cursor,
                               int* __restrict__ csr_src) {
  int e = blockIdx.x * blockDim.x + threadIdx.x;
  if (e < N_EDGES) {
    int d = ei[N_EDGES + e];
    int p = atomicAdd(&cursor[d], 1);
    csr_src[p] = ei[e];
  }
}

// ---------------- packers: fp32 -> interleaved, pre-swizzled split-bf16 ----------------
// Packed layout per row r: per 32-k step kt, a 128B group of 8x16B chunks.
// Logical chunk c = 2*kb + s (kb = k-block of 8, s = 0:hi 1:lo) stored at p = c ^ (r&7).

__global__ void convert_x(const float* __restrict__ x, unsigned short* __restrict__ xp) {
  int t = blockIdx.x * blockDim.x + threadIdx.x;
  const int npc = K0PAD / 8;
  if (t >= M_PAD * npc) return;
  int r = t / npc, g = t % npc;
  int kt = g >> 2, kb = g & 3;
  int k0 = kt * 32 + kb * 8;
  us8 hv, lv;
#pragma unroll
  for (int j = 0; j < 8; j++) {
    int k = k0 + j;
    float v = (r < N_NODES && k < IN_DIM) ? x[(long)r * IN_DIM + k] : 0.0f;
    unsigned short h, l; bsplit(v, h, l);
    hv[j] = h; lv[j] = l;
  }
  char* base = (char*)xp + (size_t)r * (4 * K0PAD) + kt * 128;
  int x7 = r & 7;
  *(us8*)(base + (((2 * kb) ^ x7) << 4)) = hv;
  *(us8*)(base + (((2 * kb + 1) ^ x7) << 4)) = lv;
}

__global__ void convert_W(const float* __restrict__ W, unsigned short* __restrict__ Wt,
                          int Kreal, int Kpad) {
  int t = blockIdx.x * blockDim.x + threadIdx.x;
  int npc = Kpad >> 3;
  if (t >= F_HID * npc) return;
  int n = t / npc, g = t % npc;
  int kt = g >> 2, kb = g & 3;
  int k0 = kt * 32 + kb * 8;
  us8 hv, lv;
#pragma unroll
  for (int j = 0; j < 8; j++) {
    int k = k0 + j;
    float v = (k < Kreal) ? W[(long)k * F_HID + n] : 0.0f;
    unsigned short h, l; bsplit(v, h, l);
    hv[j] = h; lv[j] = l;
  }
  char* base = (char*)Wt + (size_t)n * (4 * Kpad) + kt * 128;
  int x7 = n & 7;
  *(us8*)(base + (((2 * kb) ^ x7) << 4)) = hv;
  *(us8*)(base + (((2 * kb + 1) ^ x7) << 4)) = lv;
}

// ---------------- split-bf16 MFMA GEMM, fp16 output ----------------
template <int K>
__global__ __launch_bounds__(256) void gemm_mfma(const unsigned short* __restrict__ Ap,
                                                 const unsigned short* __restrict__ Bp,
                                                 _Float16* __restrict__ O) {
  constexpr int NKT = K / 32;
  constexpr size_t RB = 4 * K;
  __shared__ __align__(16) char smA[16384];
  __shared__ __align__(16) char smB[16384];
  int bm = blockIdx.x / 3, bn = blockIdx.x % 3;
  int row0 = bm * 128, col0 = bn * 128;
  int tid = threadIdx.x, lane = tid & 63, wv = tid >> 6;
  int wy = wv >> 1, wx = wv & 1;

  f32x4 acc[4][4];
#pragma unroll
  for (int i = 0; i < 4; i++)
#pragma unroll
    for (int j = 0; j < 4; j++) acc[i][j] = (f32x4)0.0f;

  const char* Ab = (const char*)Ap + (size_t)row0 * RB;
  const char* Bb = (const char*)Bp + (size_t)col0 * RB;

  int kb2 = (lane >> 4) * 2;
  int x7 = lane & 7;
  int rA = wy * 64 + (lane & 15);
  int rB = wx * 64 + (lane & 15);

  for (int kt = 0; kt < NKT; ++kt) {
#pragma unroll
    for (int i = 0; i < 4; ++i) {
      int b = wv * 4096 + i * 1024;
      int bl = b + lane * 16;
      int r = bl >> 7, q = bl & 127;
      gload16(Ab + (size_t)r * RB + kt * 128 + q, smA + b);
      gload16(Bb + (size_t)r * RB + kt * 128 + q, smB + b);
    }
    __syncthreads();

    bf16x8 ah[4], alo[4], bh[4], blo[4];
#pragma unroll
    for (int mf = 0; mf < 4; ++mf) {
      const char* p = smA + (rA + mf * 16) * 128;
      ah[mf]  = *(const bf16x8*)(p + ((kb2 ^ x7) << 4));
      alo[mf] = *(const bf16x8*)(p + (((kb2 + 1) ^ x7) << 4));
    }
#pragma unroll
    for (int nf = 0; nf < 4; ++nf) {
      const char* p = smB + (rB + nf * 16) * 128;
      bh[nf]  = *(const bf16x8*)(p + ((kb2 ^ x7) << 4));
      blo[nf] = *(const bf16x8*)(p + (((kb2 + 1) ^ x7) << 4));
    }
#pragma unroll
    for (int mf = 0; mf < 4; ++mf)
#pragma unroll
      for (int nf = 0; nf < 4; ++nf) {
        acc[mf][nf] = __builtin_amdgcn_mfma_f32_16x16x32_bf16(ah[mf], bh[nf], acc[mf][nf], 0, 0, 0);
        acc[mf][nf] = __builtin_amdgcn_mfma_f32_16x16x32_bf16(alo[mf], bh[nf], acc[mf][nf], 0, 0, 0);
        acc[mf][nf] = __builtin_amdgcn_mfma_f32_16x16x32_bf16(ah[mf], blo[nf], acc[mf][nf], 0, 0, 0);
      }
    __syncthreads();
  }

  int cr = (lane >> 4) * 4, cc = lane & 15;
#pragma unroll
  for (int mf = 0; mf < 4; ++mf)
#pragma unroll
    for (int r = 0; r < 4; ++r) {
      int row = row0 + wy * 64 + mf * 16 + cr + r;
      if (row < N_NODES) {
#pragma unroll
        for (int nf = 0; nf < 4; ++nf)
          O[(size_t)row * F_HID + col0 + wx * 64 + nf * 16 + cc] = (_Float16)acc[mf][nf][r];
      }
    }
}

// ---------------- attention dots (fp16 feat) ----------------
__global__ void dots_kernel(const _Float16* __restrict__ feat,
                            const float* __restrict__ a_src,
                            const float* __restrict__ a_dst,
                            float* __restrict__ al_s, float* __restrict__ al_d) {
  int n = (blockIdx.x * blockDim.x + threadIdx.x) >> 6;
  int lane = threadIdx.x & 63;
  if (n >= N_NODES) return;
#pragma unroll
  for (int h = 0; h < HEADS; h++) {
    float v = (float)feat[(long)n * F_HID + h * CH + lane];
    float p = v * a_src[h * CH + lane];
    float q = v * a_dst[h * CH + lane];
#pragma unroll
    for (int o = 32; o; o >>= 1) {
      p += __shfl_xor(p, o);
      q += __shfl_xor(q, o);
    }
    if (lane == 0) {
      al_s[n * HEADS + h] = p;
      al_d[n * HEADS + h] = q;
    }
  }
}

// ---------------- fused agg (hidden): online softmax + gather + bias + ELU + pack ----
// 4 nodes per block; 96 threads per node; 4 channels (f16x4) per thread.
__global__ __launch_bounds__(384) void agg_hidden(const _Float16* __restrict__ feat,
                                                  const int* __restrict__ off,
                                                  const int* __restrict__ csr_src,
                                                  const float* __restrict__ al_s,
                                                  const float* __restrict__ al_d,
                                                  const float* __restrict__ bias,
                                                  unsigned short* __restrict__ Apk) {
  int tid = threadIdx.x;
  int sub = tid / 96, t96 = tid % 96;
  int n = blockIdx.x * 4 + sub;
  int c4 = t96 * 4, h = t96 >> 4;
  int s0 = off[n], s1 = off[n + 1];
  float ad = al_d[n * HEADS + h];
  float m = -INFINITY, sum = 0.0f;
  float a0 = 0, a1 = 0, a2 = 0, a3 = 0;
  for (int i = s0; i < s1; ++i) {
    int s = csr_src[i];
    float e = al_s[s * HEADS + h] + ad;
    e = e > 0.0f ? e : 0.2f * e;
    float mn = fmaxf(m, e);
    float sc = __expf(m - mn);   // exp(-inf)=0 on first edge
    float p  = __expf(e - mn);
    m = mn;
    sum = sum * sc + p;
    f16x4 fv = *(const f16x4*)(feat + (size_t)s * F_HID + c4);
    a0 = a0 * sc + p * (float)fv[0];
    a1 = a1 * sc + p * (float)fv[1];
    a2 = a2 * sc + p * (float)fv[2];
    a3 = a3 * sc + p * (float)fv[3];
  }
  float rr = 1.0f / (sum + 1e-16f);
  float v0 = a0 * rr + bias[c4 + 0];
  float v1 = a1 * rr + bias[c4 + 1];
  float v2 = a2 * rr + bias[c4 + 2];
  float v3 = a3 * rr + bias[c4 + 3];
  v0 = v0 > 0.0f ? v0 : (__expf(v0) - 1.0f);
  v1 = v1 > 0.0f ? v1 : (__expf(v1) - 1.0f);
  v2 = v2 > 0.0f ? v2 : (__expf(v2) - 1.0f);
  v3 = v3 > 0.0f ? v3 : (__expf(v3) - 1.0f);
  unsigned short h0, l0, h1, l1, h2, l2, h3, l3;
  bsplit(v0, h0, l0);
  bsplit(v1, h1, l1);
  bsplit(v2, h2, l2);
  bsplit(v3, h3, l3);
  us4 hv, lv;
  hv[0] = h0; hv[1] = h1; hv[2] = h2; hv[3] = h3;
  lv[0] = l0; lv[1] = l1; lv[2] = l2; lv[3] = l3;
  int kt = c4 >> 5, kb = (c4 >> 3) & 3, jb = (c4 & 7) * 2;  // jb = byte offset in chunk
  char* base = (char*)Apk + (size_t)n * (4 * F_HID) + kt * 128;
  int x7 = n & 7;
  *(us4*)(base + (((2 * kb) ^ x7) << 4) + jb) = hv;
  *(us4*)(base + (((2 * kb + 1) ^ x7) << 4) + jb) = lv;
}

// ---------------- fused agg (output): online softmax + gather + head-mean + bias ----
__global__ __launch_bounds__(384) void agg_out(const _Float16* __restrict__ feat,
                                               const int* __restrict__ off,
                                               const int* __restrict__ csr_src,
                                               const float* __restrict__ al_s,
                                               const float* __restrict__ al_d,
                                               const float* __restrict__ b3,
                                               float* __restrict__ out) {
  __shared__ float red[4][384];
  int tid = threadIdx.x;
  int sub = tid / 96, t96 = tid % 96;
  int n = blockIdx.x * 4 + sub;
  int c4 = t96 * 4, h = t96 >> 4;
  int s0 = off[n], s1 = off[n + 1];
  float ad = al_d[n * HEADS + h];
  float m = -INFINITY, sum = 0.0f;
  float a0 = 0, a1 = 0, a2 = 0, a3 = 0;
  for (int i = s0; i < s1; ++i) {
    int s = csr_src[i];
    float e = al_s[s * HEADS + h] + ad;
    e = e > 0.0f ? e : 0.2f * e;
    float mn = fmaxf(m, e);
    float sc = __expf(m - mn);
    float p  = __expf(e - mn);
    m = mn;
    sum = sum * sc + p;
    f16x4 fv = *(const f16x4*)(feat + (size_t)s * F_HID + c4);
    a0 = a0 * sc + p * (float)fv[0];
    a1 = a1 * sc + p * (float)fv[1];
    a2 = a2 * sc + p * (float)fv[2];
    a3 = a3 * sc + p * (float)fv[3];
  }
  float rr = 1.0f / (sum + 1e-16f);
  red[sub][c4 + 0] = a0 * rr;
  red[sub][c4 + 1] = a1 * rr;
  red[sub][c4 + 2] = a2 * rr;
  red[sub][c4 + 3] = a3 * rr;
  __syncthreads();
  if (t96 < 16) {
    int c = t96 * 4;
    f32x4 o = (f32x4)0.0f;
#pragma unroll
    for (int hh = 0; hh < HEADS; hh++) {
#pragma unroll
      for (int j = 0; j < 4; j++) o[j] += red[sub][hh * CH + c + j];
    }
#pragma unroll
    for (int j = 0; j < 4; j++) o[j] = o[j] * (1.0f / 6.0f) + b3[c + j];
    *(f32x4*)(out + (size_t)n * CH + c) = o;
  }
}

extern "C" void kernel_launch(void* const* d_in, const int* in_sizes, int n_in,
                              void* d_out, int out_size, void* d_ws, size_t ws_size,
                              hipStream_t stream) {
  const float* x  = (const float*)d_in[0];
  const int*   ei = (const int*)d_in[1];
  const float* W_[4]  = {(const float*)d_in[2], (const float*)d_in[6],
                         (const float*)d_in[10], (const float*)d_in[14]};
  const float* AS_[4] = {(const float*)d_in[3], (const float*)d_in[7],
                         (const float*)d_in[11], (const float*)d_in[15]};
  const float* AD_[4] = {(const float*)d_in[4], (const float*)d_in[8],
                         (const float*)d_in[12], (const float*)d_in[16]};
  const float* B_[4]  = {(const float*)d_in[5], (const float*)d_in[9],
                         (const float*)d_in[13], (const float*)d_in[17]};
  float* out = (float*)d_out;

  // ---- workspace layout ----
  char* w = (char*)d_ws;
  _Float16* feat = (_Float16*)w;                  // [N,384] fp16 GEMM out
  w += (size_t)N_NODES * F_HID * 2;
  unsigned short* Apk = (unsigned short*)w;       // packed split-bf16 A (also layer-0 x)
  w += (size_t)M_PAD * 2 * F_HID * 2;
  unsigned short* Wt0 = (unsigned short*)w; w += (size_t)F_HID * 2 * K0PAD * 2;
  unsigned short* Wt1 = (unsigned short*)w; w += (size_t)F_HID * 2 * F_HID * 2;
  unsigned short* Wt2 = (unsigned short*)w; w += (size_t)F_HID * 2 * F_HID * 2;
  unsigned short* Wt3 = (unsigned short*)w; w += (size_t)F_HID * 2 * F_HID * 2;
  float* als = (float*)w; w += (size_t)N_NODES * HEADS * 4;
  float* ald = (float*)w; w += (size_t)N_NODES * HEADS * 4;
  int* off = (int*)w; w += (N_NODES + 1) * 4;
  int* cur = (int*)w; w += N_NODES * 4;
  int* deg = (int*)w; w += N_NODES * 4;
  int* csr = (int*)w;

  // ---- CSR build ----
  (void)hipMemsetAsync(deg, 0, N_NODES * sizeof(int), stream);
  count_kernel<<<cdiv(N_EDGES, 256), 256, 0, stream>>>(ei, deg);
  scan_kernel<<<1, 256, 0, stream>>>(deg, off);
  (void)hipMemcpyAsync(cur, off, N_NODES * sizeof(int), hipMemcpyDeviceToDevice, stream);
  scatter_kernel<<<cdiv(N_EDGES, 256), 256, 0, stream>>>(ei, cur, csr);

  // ---- pack inputs ----
  convert_x<<<cdiv(M_PAD * (K0PAD / 8), 256), 256, 0, stream>>>(x, Apk);
  convert_W<<<cdiv(F_HID * (K0PAD / 8), 256), 256, 0, stream>>>(W_[0], Wt0, IN_DIM, K0PAD);
  convert_W<<<cdiv(F_HID * (F_HID / 8), 256), 256, 0, stream>>>(W_[1], Wt1, F_HID, F_HID);
  convert_W<<<cdiv(F_HID * (F_HID / 8), 256), 256, 0, stream>>>(W_[2], Wt2, F_HID, F_HID);
  convert_W<<<cdiv(F_HID * (F_HID / 8), 256), 256, 0, stream>>>(W_[3], Wt3, F_HID, F_HID);
  (void)hipMemsetAsync((char*)Apk + (size_t)N_NODES * 4 * F_HID, 0,
                       (size_t)(M_PAD - N_NODES) * 4 * F_HID, stream);

  const int gemm_grid = cdiv(N_NODES, 128) * 3;
  const int dots_grid = cdiv(N_NODES, 4);
  const int agg_grid = N_NODES / 4;  // 12500

  // ---- Layer 0 (K=160 packed) ----
  gemm_mfma<K0PAD><<<gemm_grid, 256, 0, stream>>>(Apk, Wt0, feat);
  dots_kernel<<<dots_grid, 256, 0, stream>>>(feat, AS_[0], AD_[0], als, ald);
  agg_hidden<<<agg_grid, 384, 0, stream>>>(feat, off, csr, als, ald, B_[0], Apk);

  // ---- Layers 1,2 (K=384) ----
  gemm_mfma<F_HID><<<gemm_grid, 256, 0, stream>>>(Apk, Wt1, feat);
  dots_kernel<<<dots_grid, 256, 0, stream>>>(feat, AS_[1], AD_[1], als, ald);
  agg_hidden<<<agg_grid, 384, 0, stream>>>(feat, off, csr, als, ald, B_[1], Apk);

  gemm_mfma<F_HID><<<gemm_grid, 256, 0, stream>>>(Apk, Wt2, feat);
  dots_kernel<<<dots_grid, 256, 0, stream>>>(feat, AS_[2], AD_[2], als, ald);
  agg_hidden<<<agg_grid, 384, 0, stream>>>(feat, off, csr, als, ald, B_[2], Apk);

  // ---- Layer 3 (K=384, mean over heads) ----
  gemm_mfma<F_HID><<<gemm_grid, 256, 0, stream>>>(Apk, Wt3, feat);
  dots_kernel<<<dots_grid, 256, 0, stream>>>(feat, AS_[3], AD_[3], als, ald);
  agg_out<<<agg_grid, 384, 0, stream>>>(feat, off, csr, als, ald, B_[3], out);
}

// Round 5
// 906.564 us; speedup vs baseline: 2.6567x; 1.1001x over previous
//
#include <hip/hip_runtime.h>

#define N_NODES 50000
#define M_PAD 50048      // N_NODES rounded up to 128
#define N_EDGES 500000
#define HEADS 6
#define CH 64
#define F_HID 384
#define IN_DIM 131
#define K0PAD 160        // layer-0 K padded to multiple of 32
#define CAP 64           // edge chunk per node (max degree handled via chunk loop)

static inline int cdiv(int a, int b) { return (a + b - 1) / b; }

typedef __attribute__((ext_vector_type(8))) __bf16 bf16x8;
typedef __attribute__((ext_vector_type(4))) float f32x4;
typedef __attribute__((ext_vector_type(8))) unsigned short us8;
typedef __attribute__((ext_vector_type(4))) unsigned short us4;
typedef __attribute__((ext_vector_type(4))) _Float16 f16x4;

// round-to-nearest-even fp32 -> bf16 split: v ~= hi + lo
__device__ __forceinline__ void bsplit(float v, unsigned short& h, unsigned short& l) {
  unsigned u = __builtin_bit_cast(unsigned, v);
  unsigned hr = (u + 0x7FFFu + ((u >> 16) & 1u)) >> 16;
  h = (unsigned short)hr;
  float hf = __builtin_bit_cast(float, hr << 16);
  float r = v - hf;
  unsigned u2 = __builtin_bit_cast(unsigned, r);
  unsigned lr = (u2 + 0x7FFFu + ((u2 >> 16) & 1u)) >> 16;
  l = (unsigned short)lr;
}

__device__ __forceinline__ void gload16(const void* g, void* lds) {
  __builtin_amdgcn_global_load_lds((const __attribute__((address_space(1))) void*)g,
                                   (__attribute__((address_space(3))) void*)lds, 16, 0, 0);
}

// ---------------- CSR build ----------------
__global__ void count_kernel(const int* __restrict__ ei, int* __restrict__ deg) {
  int e = blockIdx.x * blockDim.x + threadIdx.x;
  if (e < N_EDGES) atomicAdd(&deg[ei[N_EDGES + e]], 1);
}

__global__ void scan_kernel(const int* __restrict__ deg, int* __restrict__ off) {
  __shared__ int sdata[256];
  int tid = threadIdx.x;
  int carry = 0;
  if (tid == 0) off[0] = 0;
  for (int base = 0; base < N_NODES; base += 1024) {
    int idx0 = base + tid * 4;
    int v[4]; int s = 0;
#pragma unroll
    for (int j = 0; j < 4; j++) {
      v[j] = (idx0 + j < N_NODES) ? deg[idx0 + j] : 0;
      s += v[j];
    }
    sdata[tid] = s;
    __syncthreads();
    for (int o = 1; o < 256; o <<= 1) {
      int x = (tid >= o) ? sdata[tid - o] : 0;
      __syncthreads();
      sdata[tid] += x;
      __syncthreads();
    }
    int excl = sdata[tid] - s + carry;
    int total = sdata[255];
    int run = excl;
#pragma unroll
    for (int j = 0; j < 4; j++) {
      run += v[j];
      if (idx0 + j < N_NODES) off[idx0 + j + 1] = run;
    }
    carry += total;
    __syncthreads();
  }
}

__global__ void scatter_kernel(const int* __restrict__ ei, int* __restrict__ cursor,
                               int* __restrict__ csr_src) {
  int e = blockIdx.x * blockDim.x + threadIdx.x;
  if (e < N_EDGES) {
    int d = ei[N_EDGES + e];
    int p = atomicAdd(&cursor[d], 1);
    csr_src[p] = ei[e];
  }
}

// ---------------- packers: fp32 -> interleaved, pre-swizzled split-bf16 ----------------
// Packed layout per row r: per 32-k step kt, a 128B group of 8x16B chunks.
// Logical chunk c = 2*kb + s (kb = k-block of 8, s = 0:hi 1:lo) stored at p = c ^ (r&7).

__global__ void convert_x(const float* __restrict__ x, unsigned short* __restrict__ xp) {
  int t = blockIdx.x * blockDim.x + threadIdx.x;
  const int npc = K0PAD / 8;
  if (t >= M_PAD * npc) return;
  int r = t / npc, g = t % npc;
  int kt = g >> 2, kb = g & 3;
  int k0 = kt * 32 + kb * 8;
  us8 hv, lv;
#pragma unroll
  for (int j = 0; j < 8; j++) {
    int k = k0 + j;
    float v = (r < N_NODES && k < IN_DIM) ? x[(long)r * IN_DIM + k] : 0.0f;
    unsigned short h, l; bsplit(v, h, l);
    hv[j] = h; lv[j] = l;
  }
  char* base = (char*)xp + (size_t)r * (4 * K0PAD) + kt * 128;
  int x7 = r & 7;
  *(us8*)(base + (((2 * kb) ^ x7) << 4)) = hv;
  *(us8*)(base + (((2 * kb + 1) ^ x7) << 4)) = lv;
}

__global__ void convert_W(const float* __restrict__ W, unsigned short* __restrict__ Wt,
                          int Kreal, int Kpad) {
  int t = blockIdx.x * blockDim.x + threadIdx.x;
  int npc = Kpad >> 3;
  if (t >= F_HID * npc) return;
  int n = t / npc, g = t % npc;
  int kt = g >> 2, kb = g & 3;
  int k0 = kt * 32 + kb * 8;
  us8 hv, lv;
#pragma unroll
  for (int j = 0; j < 8; j++) {
    int k = k0 + j;
    float v = (k < Kreal) ? W[(long)k * F_HID + n] : 0.0f;
    unsigned short h, l; bsplit(v, h, l);
    hv[j] = h; lv[j] = l;
  }
  char* base = (char*)Wt + (size_t)n * (4 * Kpad) + kt * 128;
  int x7 = n & 7;
  *(us8*)(base + (((2 * kb) ^ x7) << 4)) = hv;
  *(us8*)(base + (((2 * kb + 1) ^ x7) << 4)) = lv;
}

// ---------------- split-bf16 MFMA GEMM, fp16 output ----------------
template <int K>
__global__ __launch_bounds__(256) void gemm_mfma(const unsigned short* __restrict__ Ap,
                                                 const unsigned short* __restrict__ Bp,
                                                 _Float16* __restrict__ O) {
  constexpr int NKT = K / 32;
  constexpr size_t RB = 4 * K;
  __shared__ __align__(16) char smA[16384];
  __shared__ __align__(16) char smB[16384];
  int bm = blockIdx.x / 3, bn = blockIdx.x % 3;
  int row0 = bm * 128, col0 = bn * 128;
  int tid = threadIdx.x, lane = tid & 63, wv = tid >> 6;
  int wy = wv >> 1, wx = wv & 1;

  f32x4 acc[4][4];
#pragma unroll
  for (int i = 0; i < 4; i++)
#pragma unroll
    for (int j = 0; j < 4; j++) acc[i][j] = (f32x4)0.0f;

  const char* Ab = (const char*)Ap + (size_t)row0 * RB;
  const char* Bb = (const char*)Bp + (size_t)col0 * RB;

  int kb2 = (lane >> 4) * 2;
  int x7 = lane & 7;
  int rA = wy * 64 + (lane & 15);
  int rB = wx * 64 + (lane & 15);

  for (int kt = 0; kt < NKT; ++kt) {
#pragma unroll
    for (int i = 0; i < 4; ++i) {
      int b = wv * 4096 + i * 1024;
      int bl = b + lane * 16;
      int r = bl >> 7, q = bl & 127;
      gload16(Ab + (size_t)r * RB + kt * 128 + q, smA + b);
      gload16(Bb + (size_t)r * RB + kt * 128 + q, smB + b);
    }
    __syncthreads();

    bf16x8 ah[4], alo[4], bh[4], blo[4];
#pragma unroll
    for (int mf = 0; mf < 4; ++mf) {
      const char* p = smA + (rA + mf * 16) * 128;
      ah[mf]  = *(const bf16x8*)(p + ((kb2 ^ x7) << 4));
      alo[mf] = *(const bf16x8*)(p + (((kb2 + 1) ^ x7) << 4));
    }
#pragma unroll
    for (int nf = 0; nf < 4; ++nf) {
      const char* p = smB + (rB + nf * 16) * 128;
      bh[nf]  = *(const bf16x8*)(p + ((kb2 ^ x7) << 4));
      blo[nf] = *(const bf16x8*)(p + (((kb2 + 1) ^ x7) << 4));
    }
#pragma unroll
    for (int mf = 0; mf < 4; ++mf)
#pragma unroll
      for (int nf = 0; nf < 4; ++nf) {
        acc[mf][nf] = __builtin_amdgcn_mfma_f32_16x16x32_bf16(ah[mf], bh[nf], acc[mf][nf], 0, 0, 0);
        acc[mf][nf] = __builtin_amdgcn_mfma_f32_16x16x32_bf16(alo[mf], bh[nf], acc[mf][nf], 0, 0, 0);
        acc[mf][nf] = __builtin_amdgcn_mfma_f32_16x16x32_bf16(ah[mf], blo[nf], acc[mf][nf], 0, 0, 0);
      }
    __syncthreads();
  }

  int cr = (lane >> 4) * 4, cc = lane & 15;
#pragma unroll
  for (int mf = 0; mf < 4; ++mf)
#pragma unroll
    for (int r = 0; r < 4; ++r) {
      int row = row0 + wy * 64 + mf * 16 + cr + r;
      if (row < N_NODES) {
#pragma unroll
        for (int nf = 0; nf < 4; ++nf)
          O[(size_t)row * F_HID + col0 + wx * 64 + nf * 16 + cc] = (_Float16)acc[mf][nf][r];
      }
    }
}

// ---------------- attention dots (fp16 feat) ----------------
__global__ void dots_kernel(const _Float16* __restrict__ feat,
                            const float* __restrict__ a_src,
                            const float* __restrict__ a_dst,
                            float* __restrict__ al_s, float* __restrict__ al_d) {
  int n = (blockIdx.x * blockDim.x + threadIdx.x) >> 6;
  int lane = threadIdx.x & 63;
  if (n >= N_NODES) return;
#pragma unroll
  for (int h = 0; h < HEADS; h++) {
    float v = (float)feat[(long)n * F_HID + h * CH + lane];
    float p = v * a_src[h * CH + lane];
    float q = v * a_dst[h * CH + lane];
#pragma unroll
    for (int o = 32; o; o >>= 1) {
      p += __shfl_xor(p, o);
      q += __shfl_xor(q, o);
    }
    if (lane == 0) {
      al_s[n * HEADS + h] = p;
      al_d[n * HEADS + h] = q;
    }
  }
}

// ---------------- phase-split agg core (shared by hidden / out) ----------------
// Block: 384 threads = 4 nodes x 96 threads. Per 64-edge chunk:
//   A) parallel logit computation into LDS (deg x 6 items over 96 threads)
//   B) 24 threads (node x head) do max/exp/sum scan, write weights back
//   C) gather loop: pure FMA over independent global loads, LDS-broadcast weights
// Cross-chunk online rescale keeps any degree correct (chunk loop ~always 1 iter).

#define AGG_CORE(FEAT, OFF, CSR, ALS, ALD)                                        \
  int tid = threadIdx.x;                                                          \
  int sub = tid / 96, t96 = tid - sub * 96;                                       \
  int nb = blockIdx.x * 4;                                                        \
  int n = nb + sub;                                                               \
  int c4 = t96 * 4, h = t96 >> 4;                                                 \
  int o_[5];                                                                      \
  _Pragma("unroll")                                                               \
  for (int k = 0; k < 5; ++k) o_[k] = OFF[nb + k];                                \
  int dmax = 0;                                                                   \
  _Pragma("unroll")                                                               \
  for (int k = 0; k < 4; ++k) dmax = max(dmax, o_[k + 1] - o_[k]);                \
  int nch = (dmax + CAP - 1) / CAP; if (nch < 1) nch = 1;                         \
  int s0 = o_[sub], deg = o_[sub + 1] - o_[sub];                                  \
  int bsub = tid / 6, bh = tid - bsub * 6;                                        \
  int bs0 = 0, bdeg = 0;                                                          \
  if (tid < 24) { bs0 = o_[bsub]; bdeg = o_[bsub + 1] - o_[bsub]; }               \
  (void)bs0;                                                                      \
  float m_run = -INFINITY, s_run = 0.0f;                                          \
  float a0 = 0, a1 = 0, a2 = 0, a3 = 0;                                           \
  for (int ch = 0; ch < nch; ++ch) {                                              \
    int base = ch * CAP;                                                          \
    int cl = deg - base; cl = cl < 0 ? 0 : (cl > CAP ? CAP : cl);                 \
    if (t96 < cl) lsrc[sub][t96] = CSR[s0 + base + t96];                          \
    for (int j = t96; j < cl * 6; j += 96) {                                      \
      int i = j / 6, hh = j - i * 6;                                              \
      int s = CSR[s0 + base + i];                                                 \
      float e = ALS[s * 6 + hh] + ALD[n * 6 + hh];                                \
      e = e > 0.0f ? e : 0.2f * e;                                                \
      lew[sub][hh][i] = e;                                                        \
    }                                                                             \
    __syncthreads();                                                              \
    if (tid < 24) {                                                               \
      int bcl = bdeg - base; bcl = bcl < 0 ? 0 : (bcl > CAP ? CAP : bcl);         \
      float asc;                                                                  \
      if (bcl > 0) {                                                              \
        float mc = -INFINITY;                                                     \
        for (int i = 0; i < bcl; ++i) mc = fmaxf(mc, lew[bsub][bh][i]);           \
        float mn = fmaxf(m_run, mc);                                              \
        asc = (m_run == -INFINITY) ? 0.0f : __expf(m_run - mn);                   \
        float sc = 0.0f;                                                          \
        for (int i = 0; i < bcl; ++i) {                                           \
          float wv = __expf(lew[bsub][bh][i] - mn);                               \
          lew[bsub][bh][i] = wv;                                                  \
          sc += wv;                                                               \
        }                                                                         \
        s_run = s_run * asc + sc;                                                 \
        m_run = mn;                                                               \
      } else asc = 1.0f;                                                          \
      lasc[bsub][bh] = asc;                                                       \
      if (ch == nch - 1) lrr[bsub][bh] = 1.0f / (s_run + 1e-16f);                 \
    }                                                                             \
    __syncthreads();                                                              \
    float cc0 = 0, cc1 = 0, cc2 = 0, cc3 = 0;                                     \
    for (int i = 0; i < cl; ++i) {                                                \
      int s = lsrc[sub][i];                                                       \
      float wv = lew[sub][h][i];                                                  \
      f16x4 fv = *(const f16x4*)(FEAT + (size_t)s * F_HID + c4);                  \
      cc0 += wv * (float)fv[0];                                                   \
      cc1 += wv * (float)fv[1];                                                   \
      cc2 += wv * (float)fv[2];                                                   \
      cc3 += wv * (float)fv[3];                                                   \
    }                                                                             \
    float asc2 = lasc[sub][h];                                                    \
    a0 = a0 * asc2 + cc0; a1 = a1 * asc2 + cc1;                                   \
    a2 = a2 * asc2 + cc2; a3 = a3 * asc2 + cc3;                                   \
    __syncthreads();                                                              \
  }                                                                               \
  float rr = lrr[sub][h];

// hidden layers: normalize + bias + ELU + split-bf16 pack
__global__ __launch_bounds__(384) void agg_hidden(const _Float16* __restrict__ feat,
                                                  const int* __restrict__ off,
                                                  const int* __restrict__ csr_src,
                                                  const float* __restrict__ al_s,
                                                  const float* __restrict__ al_d,
                                                  const float* __restrict__ bias,
                                                  unsigned short* __restrict__ Apk) {
  __shared__ int   lsrc[4][CAP + 1];
  __shared__ float lew[4][6][CAP + 1];
  __shared__ float lasc[4][6];
  __shared__ float lrr[4][6];
  AGG_CORE(feat, off, csr_src, al_s, al_d)
  float v0 = a0 * rr + bias[c4 + 0];
  float v1 = a1 * rr + bias[c4 + 1];
  float v2 = a2 * rr + bias[c4 + 2];
  float v3 = a3 * rr + bias[c4 + 3];
  v0 = v0 > 0.0f ? v0 : (__expf(v0) - 1.0f);
  v1 = v1 > 0.0f ? v1 : (__expf(v1) - 1.0f);
  v2 = v2 > 0.0f ? v2 : (__expf(v2) - 1.0f);
  v3 = v3 > 0.0f ? v3 : (__expf(v3) - 1.0f);
  unsigned short h0, l0, h1, l1, h2, l2, h3, l3;
  bsplit(v0, h0, l0);
  bsplit(v1, h1, l1);
  bsplit(v2, h2, l2);
  bsplit(v3, h3, l3);
  us4 hv, lv;
  hv[0] = h0; hv[1] = h1; hv[2] = h2; hv[3] = h3;
  lv[0] = l0; lv[1] = l1; lv[2] = l2; lv[3] = l3;
  int kt = c4 >> 5, kb = (c4 >> 3) & 3, jb = (c4 & 7) * 2;
  char* basep = (char*)Apk + (size_t)n * (4 * F_HID) + kt * 128;
  int x7 = n & 7;
  *(us4*)(basep + (((2 * kb) ^ x7) << 4) + jb) = hv;
  *(us4*)(basep + (((2 * kb + 1) ^ x7) << 4) + jb) = lv;
}

// output layer: normalize + head-mean + bias
__global__ __launch_bounds__(384) void agg_out(const _Float16* __restrict__ feat,
                                               const int* __restrict__ off,
                                               const int* __restrict__ csr_src,
                                               const float* __restrict__ al_s,
                                               const float* __restrict__ al_d,
                                               const float* __restrict__ b3,
                                               float* __restrict__ out) {
  __shared__ int   lsrc[4][CAP + 1];
  __shared__ float lew[4][6][CAP + 1];
  __shared__ float lasc[4][6];
  __shared__ float lrr[4][6];
  __shared__ float red[4][384];
  AGG_CORE(feat, off, csr_src, al_s, al_d)
  red[sub][c4 + 0] = a0 * rr;
  red[sub][c4 + 1] = a1 * rr;
  red[sub][c4 + 2] = a2 * rr;
  red[sub][c4 + 3] = a3 * rr;
  __syncthreads();
  if (t96 < 16) {
    int c = t96 * 4;
    f32x4 o = (f32x4)0.0f;
#pragma unroll
    for (int hh = 0; hh < HEADS; hh++) {
#pragma unroll
      for (int j = 0; j < 4; j++) o[j] += red[sub][hh * CH + c + j];
    }
#pragma unroll
    for (int j = 0; j < 4; j++) o[j] = o[j] * (1.0f / 6.0f) + b3[c + j];
    *(f32x4*)(out + (size_t)n * CH + c) = o;
  }
}

extern "C" void kernel_launch(void* const* d_in, const int* in_sizes, int n_in,
                              void* d_out, int out_size, void* d_ws, size_t ws_size,
                              hipStream_t stream) {
  const float* x  = (const float*)d_in[0];
  const int*   ei = (const int*)d_in[1];
  const float* W_[4]  = {(const float*)d_in[2], (const float*)d_in[6],
                         (const float*)d_in[10], (const float*)d_in[14]};
  const float* AS_[4] = {(const float*)d_in[3], (const float*)d_in[7],
                         (const float*)d_in[11], (const float*)d_in[15]};
  const float* AD_[4] = {(const float*)d_in[4], (const float*)d_in[8],
                         (const float*)d_in[12], (const float*)d_in[16]};
  const float* B_[4]  = {(const float*)d_in[5], (const float*)d_in[9],
                         (const float*)d_in[13], (const float*)d_in[17]};
  float* out = (float*)d_out;

  // ---- workspace layout ----
  char* w = (char*)d_ws;
  _Float16* feat = (_Float16*)w;                  // [N,384] fp16 GEMM out
  w += (size_t)N_NODES * F_HID * 2;
  unsigned short* Apk = (unsigned short*)w;       // packed split-bf16 A (also layer-0 x)
  w += (size_t)M_PAD * 2 * F_HID * 2;
  unsigned short* Wt0 = (unsigned short*)w; w += (size_t)F_HID * 2 * K0PAD * 2;
  unsigned short* Wt1 = (unsigned short*)w; w += (size_t)F_HID * 2 * F_HID * 2;
  unsigned short* Wt2 = (unsigned short*)w; w += (size_t)F_HID * 2 * F_HID * 2;
  unsigned short* Wt3 = (unsigned short*)w; w += (size_t)F_HID * 2 * F_HID * 2;
  float* als = (float*)w; w += (size_t)N_NODES * HEADS * 4;
  float* ald = (float*)w; w += (size_t)N_NODES * HEADS * 4;
  int* off = (int*)w; w += (N_NODES + 1) * 4;
  int* cur = (int*)w; w += N_NODES * 4;
  int* deg = (int*)w; w += N_NODES * 4;
  int* csr = (int*)w;

  // ---- CSR build ----
  (void)hipMemsetAsync(deg, 0, N_NODES * sizeof(int), stream);
  count_kernel<<<cdiv(N_EDGES, 256), 256, 0, stream>>>(ei, deg);
  scan_kernel<<<1, 256, 0, stream>>>(deg, off);
  (void)hipMemcpyAsync(cur, off, N_NODES * sizeof(int), hipMemcpyDeviceToDevice, stream);
  scatter_kernel<<<cdiv(N_EDGES, 256), 256, 0, stream>>>(ei, cur, csr);

  // ---- pack inputs ----
  convert_x<<<cdiv(M_PAD * (K0PAD / 8), 256), 256, 0, stream>>>(x, Apk);
  convert_W<<<cdiv(F_HID * (K0PAD / 8), 256), 256, 0, stream>>>(W_[0], Wt0, IN_DIM, K0PAD);
  convert_W<<<cdiv(F_HID * (F_HID / 8), 256), 256, 0, stream>>>(W_[1], Wt1, F_HID, F_HID);
  convert_W<<<cdiv(F_HID * (F_HID / 8), 256), 256, 0, stream>>>(W_[2], Wt2, F_HID, F_HID);
  convert_W<<<cdiv(F_HID * (F_HID / 8), 256), 256, 0, stream>>>(W_[3], Wt3, F_HID, F_HID);
  (void)hipMemsetAsync((char*)Apk + (size_t)N_NODES * 4 * F_HID, 0,
                       (size_t)(M_PAD - N_NODES) * 4 * F_HID, stream);

  const int gemm_grid = cdiv(N_NODES, 128) * 3;
  const int dots_grid = cdiv(N_NODES, 4);
  const int agg_grid = N_NODES / 4;  // 12500

  // ---- Layer 0 (K=160 packed) ----
  gemm_mfma<K0PAD><<<gemm_grid, 256, 0, stream>>>(Apk, Wt0, feat);
  dots_kernel<<<dots_grid, 256, 0, stream>>>(feat, AS_[0], AD_[0], als, ald);
  agg_hidden<<<agg_grid, 384, 0, stream>>>(feat, off, csr, als, ald, B_[0], Apk);

  // ---- Layers 1,2 (K=384) ----
  gemm_mfma<F_HID><<<gemm_grid, 256, 0, stream>>>(Apk, Wt1, feat);
  dots_kernel<<<dots_grid, 256, 0, stream>>>(feat, AS_[1], AD_[1], als, ald);
  agg_hidden<<<agg_grid, 384, 0, stream>>>(feat, off, csr, als, ald, B_[1], Apk);

  gemm_mfma<F_HID><<<gemm_grid, 256, 0, stream>>>(Apk, Wt2, feat);
  dots_kernel<<<dots_grid, 256, 0, stream>>>(feat, AS_[2], AD_[2], als, ald);
  agg_hidden<<<agg_grid, 384, 0, stream>>>(feat, off, csr, als, ald, B_[2], Apk);

  // ---- Layer 3 (K=384, mean over heads) ----
  gemm_mfma<F_HID><<<gemm_grid, 256, 0, stream>>>(Apk, Wt3, feat);
  dots_kernel<<<dots_grid, 256, 0, stream>>>(feat, AS_[3], AD_[3], als, ald);
  agg_out<<<agg_grid, 384, 0, stream>>>(feat, off, csr, als, ald, B_[3], out);
}